// Round 3
// baseline (557.917 us; speedup 1.0000x reference)
//
#include <hip/hip_runtime.h>
#include <hip/hip_bf16.h>

#define B_ 256
#define N_ 256
#define H_ 16
// softmax scale folded with log2(e); bias folded with log2(e)
#define SCALE2_ 0.25504526484f   // (1/sqrt(32)) * log2(e)
#define LOG2E_ 1.4426950408889634f

typedef __attribute__((ext_vector_type(8))) short short8;
typedef __attribute__((ext_vector_type(4))) float f32x4v;
typedef unsigned int u32;

// async global->LDS, 16B per lane. LDS dest must be wave-uniform base (+lane*16).
#define GLOAD16(gptr, lptr)                                                        \
  __builtin_amdgcn_global_load_lds((const __attribute__((address_space(1))) u32*)(gptr), \
                                   (__attribute__((address_space(3))) u32*)(lptr), 16, 0, 0)

static __device__ __forceinline__ unsigned short f2bf(float f) {
  union { float f; unsigned u; } x; x.f = f;
  unsigned r = x.u + 0x7fffu + ((x.u >> 16) & 1u);
  return (unsigned short)(r >> 16);
}
static __device__ __forceinline__ unsigned cvt_pk_bf16(float lo, float hi) {
  unsigned r;
  asm("v_cvt_pk_bf16_f32 %0, %1, %2" : "=v"(r) : "v"(lo), "v"(hi));
  return r;
}

// ---- converters ----
__global__ void cvt_x_kernel(const float* __restrict__ in, unsigned short* __restrict__ out, int n8) {
  int i = blockIdx.x * 256 + threadIdx.x;
  int stride = gridDim.x * 256;
  for (; i < n8; i += stride) {
    const float4* p = reinterpret_cast<const float4*>(in + (size_t)i * 8);
    float4 a = p[0], b = p[1];
    ushort4 r0 = make_ushort4(f2bf(a.x), f2bf(a.y), f2bf(a.z), f2bf(a.w));
    ushort4 r1 = make_ushort4(f2bf(b.x), f2bf(b.y), f2bf(b.z), f2bf(b.w));
    ushort4* q = reinterpret_cast<ushort4*>(out + (size_t)i * 8);
    q[0] = r0; q[1] = r1;
  }
}

// transpose+convert W [512][ncols] f32 -> WT [ncols][512] bf16
__global__ void cvt_wT_kernel(const float* __restrict__ in, unsigned short* __restrict__ out, int ncols) {
  __shared__ float tile[32][65];
  const int nb = ncols >> 6;
  const int k0 = (blockIdx.x / nb) << 5;
  const int n0 = (blockIdx.x % nb) << 6;
  const int t = threadIdx.x;
  {
    int kk = t >> 3, c0 = (t & 7) << 3;
    const float* src = in + (size_t)(k0 + kk) * ncols + n0 + c0;
    float4 v0 = *reinterpret_cast<const float4*>(src);
    float4 v1 = *reinterpret_cast<const float4*>(src + 4);
    tile[kk][c0 + 0] = v0.x; tile[kk][c0 + 1] = v0.y; tile[kk][c0 + 2] = v0.z; tile[kk][c0 + 3] = v0.w;
    tile[kk][c0 + 4] = v1.x; tile[kk][c0 + 5] = v1.y; tile[kk][c0 + 6] = v1.z; tile[kk][c0 + 7] = v1.w;
  }
  __syncthreads();
  {
    int nn = t >> 2, c0 = (t & 3) << 3;
    unsigned short* dst = out + (size_t)(n0 + nn) * 512 + k0 + c0;
    ushort4 a = make_ushort4(f2bf(tile[c0 + 0][nn]), f2bf(tile[c0 + 1][nn]),
                             f2bf(tile[c0 + 2][nn]), f2bf(tile[c0 + 3][nn]));
    ushort4 b = make_ushort4(f2bf(tile[c0 + 4][nn]), f2bf(tile[c0 + 5][nn]),
                             f2bf(tile[c0 + 6][nn]), f2bf(tile[c0 + 7][nn]));
    *reinterpret_cast<ushort4*>(dst) = a;
    *reinterpret_cast<ushort4*>(dst + 4) = b;
  }
}

// K0: tm[b][j] = temb[b]@temb_w[:,j] + temb_b[j] + qkv_b[j]; 4 b per block
__global__ void temb_mod_kernel(const float* __restrict__ temb,
                                const float* __restrict__ temb_w,
                                const float* __restrict__ temb_b,
                                const float* __restrict__ qkv_b,
                                float* __restrict__ tm) {
  __shared__ float ts[4][512];
  const int b0 = blockIdx.x << 2, t = threadIdx.x;
  for (int i = t; i < 2048; i += 256) ts[i >> 9][i & 511] = temb[(size_t)b0 * 512 + i];
  __syncthreads();
  float acc[4][6];
#pragma unroll
  for (int u = 0; u < 6; ++u) {
    float bsum = temb_b[t + u * 256] + qkv_b[t + u * 256];
#pragma unroll
    for (int bb = 0; bb < 4; ++bb) acc[bb][u] = bsum;
  }
  for (int k = 0; k < 512; ++k) {
    float t0 = ts[0][k], t1 = ts[1][k], t2 = ts[2][k], t3 = ts[3][k];
#pragma unroll
    for (int u = 0; u < 6; ++u) {
      float wv = temb_w[(size_t)k * 1536 + t + u * 256];
      acc[0][u] += t0 * wv; acc[1][u] += t1 * wv; acc[2][u] += t2 * wv; acc[3][u] += t3 * wv;
    }
  }
#pragma unroll
  for (int bb = 0; bb < 4; ++bb)
#pragma unroll
    for (int u = 0; u < 6; ++u) tm[(size_t)(b0 + bb) * 1536 + t + u * 256] = acc[bb][u];
}

// K1: fused qkv-GEMM + flash attention per (b,h). 512 thr, 8 waves, 3 blk/CU.
// All LDS arrays stride-32 shorts with XOR-16B-unit swizzle (unit ^= (row>>1)&3,
// vTs: unit ^= row&7). Staging swizzle via pre-swizzled per-lane global src.
__global__ __launch_bounds__(512, 6)
void fused_attn_kernel(const unsigned short* __restrict__ xb16,   // [65536][512]
                       const unsigned short* __restrict__ wT,     // [1536][512]
                       const float* __restrict__ rpb,
                       const float* __restrict__ tm,
                       unsigned short* __restrict__ attn_out) {
  // [0,16384)      xs [256][32]  -> qs after phase A
  // [16384,32768)  ks [256][32]; first 6144B = wTs[96][32] during phase A
  // [32768,49152)  vTs [32][256] (permuted cols c=2*(k&15)+(k>>4&1), swizzled)
  // [49152,52996)  biasT f32[961] (pre-scaled by log2e)
  __shared__ __align__(16) char smem[53008];
  short* xs  = (short*)smem;
  short* ks  = (short*)(smem + 16384);
  short* vTs = (short*)(smem + 32768);
  float* biasT = (float*)(smem + 49152);

  const int bh = blockIdx.x;
  const int b = bh >> 4, h = bh & 15;
  const int tid = threadIdx.x;
  const int w = tid >> 6, l = tid & 63;
  const int l16 = l & 15, g = l >> 4;
  const int gsw8 = (g ^ ((l16 >> 1) & 3)) << 3;          // swizzled frag offset (shorts)
  const int lrow = l >> 2;
  const int lcol = (((l & 3) ^ ((l >> 3) & 3)) << 3);    // swizzled source col

  const unsigned short* xsrc0 = xb16 + (size_t)(b * 256 + w * 16 + lrow) * 512 + lcol;
  const unsigned short* xsrc1 = xsrc0 + (size_t)128 * 512;
  const int row96 = w * 16 + lrow;
  const unsigned short* wsrc = wT + (size_t)((row96 >> 5) * 512 + h * 32 + (row96 & 31)) * 512 + lcol;
  short* ldsX0 = xs + w * 512;
  short* ldsX1 = xs + (8 + w) * 512;
  short* ldsW  = ks + w * 512;   // wTs region (w < 6)

  f32x4v acc[2][6];
#pragma unroll
  for (int mt = 0; mt < 2; ++mt)
#pragma unroll
    for (int nt = 0; nt < 6; ++nt) acc[mt][nt] = (f32x4v)(0.0f);

  // ---- Phase A: qkv = x[b] @ wT(96 rows of head h) ----
  for (int k0 = 0; k0 < 512; k0 += 32) {
    GLOAD16(xsrc0 + k0, ldsX0);
    GLOAD16(xsrc1 + k0, ldsX1);
    if (w < 6) GLOAD16(wsrc + k0, ldsW);
    __syncthreads();
    short8 af[2], bfr[6];
#pragma unroll
    for (int mt = 0; mt < 2; ++mt)
      af[mt] = *reinterpret_cast<short8*>(&xs[(w * 32 + mt * 16 + l16) * 32 + gsw8]);
#pragma unroll
    for (int nt = 0; nt < 6; ++nt)
      bfr[nt] = *reinterpret_cast<short8*>(&ks[(nt * 16 + l16) * 32 + gsw8]);
#pragma unroll
    for (int mt = 0; mt < 2; ++mt)
#pragma unroll
      for (int nt = 0; nt < 6; ++nt)
        acc[mt][nt] = __builtin_amdgcn_mfma_f32_16x16x32_bf16(af[mt], bfr[nt], acc[mt][nt], 0, 0, 0);
    __syncthreads();
  }

  // ---- epilogue A: +tm bias; q (log2-scaled) -> xs, k -> ks, v -> vTs (permuted) ----
  const float* tmb = tm + (size_t)b * 1536 + h * 32;
#pragma unroll
  for (int nt = 0; nt < 6; ++nt) {
    const int prt = nt >> 1;
    const int d = ((nt & 1) << 4) + l16;
    const float tmv = tmb[(prt << 9) + d];
#pragma unroll
    for (int mt = 0; mt < 2; ++mt) {
      const int r0 = w * 32 + mt * 16 + g * 4;
#pragma unroll
      for (int j = 0; j < 4; ++j) {
        const int row = r0 + j;
        const float val = acc[mt][nt][j] + tmv;
        if (prt == 0) {
          const int unit = ((d >> 3) ^ ((row >> 1) & 3));
          xs[row * 32 + (unit << 3) + (d & 7)] = (short)f2bf(val * SCALE2_);
        } else if (prt == 1) {
          const int unit = ((d >> 3) ^ ((row >> 1) & 3));
          ks[row * 32 + (unit << 3) + (d & 7)] = (short)f2bf(val);
        } else {
          const int key = row;
          const int vcol = ((key >> 5) << 5) | (((key & 15) << 1) | ((key >> 4) & 1));
          const int unit = ((vcol >> 3) ^ (d & 7));
          vTs[d * 256 + (unit << 3) + (vcol & 7)] = (short)f2bf(val);
        }
      }
    }
  }
  for (int e = tid; e < 961; e += 512) biasT[e] = rpb[e * 16 + h] * LOG2E_;
  __syncthreads();

  // ---- flash attention: S^T = mfma(K, Q); P stays in registers ----
  short8 bq[2];
#pragma unroll
  for (int mt = 0; mt < 2; ++mt)
    bq[mt] = *reinterpret_cast<short8*>(&xs[(w * 32 + mt * 16 + l16) * 32 + gsw8]);

  float m2 = -1.0e30f, lsum0 = 0.0f, lsum1 = 0.0f;
  f32x4v oacc[2][2];
#pragma unroll
  for (int mt = 0; mt < 2; ++mt)
#pragma unroll
    for (int nt = 0; nt < 2; ++nt) oacc[mt][nt] = (f32x4v)(0.0f);

  const int bcol = l16 - (g << 2) + 15;    // [0,30]
  const int brow0 = w * 2 + 15;

  for (int kc = 0; kc < 8; ++kc) {
    float sv[2][2][4];   // [ct][mt][j]: key = kc*32+ct*16+g*4+j, query = w*32+mt*16+l16
#pragma unroll
    for (int ct = 0; ct < 2; ++ct) {
      const int kt = kc * 2 + ct;
      short8 kf = *reinterpret_cast<short8*>(&ks[(kt * 16 + l16) * 32 + gsw8]);
#pragma unroll
      for (int mt = 0; mt < 2; ++mt) {
        f32x4v s4 = __builtin_amdgcn_mfma_f32_16x16x32_bf16(kf, bq[mt], (f32x4v)(0.0f), 0, 0, 0);
        const float* bp = biasT + (brow0 + mt - kt) * 31 + bcol;
#pragma unroll
        for (int j = 0; j < 4; ++j) sv[ct][mt][j] = s4[j] + bp[-j];
      }
    }
    // wave-common running max (any m >= rowmax is valid; m cancels in sum)
    float c0 = fmaxf(fmaxf(sv[0][0][0], sv[0][0][1]), fmaxf(sv[0][0][2], sv[0][0][3]));
    float c1 = fmaxf(fmaxf(sv[0][1][0], sv[0][1][1]), fmaxf(sv[0][1][2], sv[0][1][3]));
    float c2 = fmaxf(fmaxf(sv[1][0][0], sv[1][0][1]), fmaxf(sv[1][0][2], sv[1][0][3]));
    float c3 = fmaxf(fmaxf(sv[1][1][0], sv[1][1][1]), fmaxf(sv[1][1][2], sv[1][1][3]));
    float cm = fmaxf(fmaxf(c0, c1), fmaxf(c2, c3));
    cm = fmaxf(cm, __shfl_xor(cm, 1));
    cm = fmaxf(cm, __shfl_xor(cm, 2));
    cm = fmaxf(cm, __shfl_xor(cm, 4));
    cm = fmaxf(cm, __shfl_xor(cm, 8));
    cm = fmaxf(cm, __shfl_xor(cm, 16));
    cm = fmaxf(cm, __shfl_xor(cm, 32));
    if (cm > m2 + 8.0f) {               // defer-rescale (wave-uniform)
      const float r = exp2f(m2 - cm);
      m2 = cm;
      lsum0 *= r; lsum1 *= r;
      oacc[0][0] *= r; oacc[0][1] *= r; oacc[1][0] *= r; oacc[1][1] *= r;
    }
    short8 pa[2];
    {
      union { u32 u[4]; short8 s; } pk0, pk1;
#pragma unroll
      for (int j = 0; j < 4; ++j) {
        const float a0 = exp2f(sv[0][0][j] - m2);
        const float a1 = exp2f(sv[1][0][j] - m2);
        lsum0 += a0 + a1;
        pk0.u[j] = cvt_pk_bf16(a0, a1);
        const float b0v = exp2f(sv[0][1][j] - m2);
        const float b1v = exp2f(sv[1][1][j] - m2);
        lsum1 += b0v + b1v;
        pk1.u[j] = cvt_pk_bf16(b0v, b1v);
      }
      pa[0] = pk0.s; pa[1] = pk1.s;
    }
#pragma unroll
    for (int nt = 0; nt < 2; ++nt) {
      short8 bv = *reinterpret_cast<short8*>(
          &vTs[(nt * 16 + l16) * 256 + ((((kc * 4 + g) ^ (l16 & 7)) << 3))]);
#pragma unroll
      for (int mt = 0; mt < 2; ++mt)
        oacc[mt][nt] = __builtin_amdgcn_mfma_f32_16x16x32_bf16(pa[mt], bv, oacc[mt][nt], 0, 0, 0);
    }
  }

  // ---- normalize + write ----
  lsum0 += __shfl_xor(lsum0, 16); lsum0 += __shfl_xor(lsum0, 32);
  lsum1 += __shfl_xor(lsum1, 16); lsum1 += __shfl_xor(lsum1, 32);
  unsigned short* ao = attn_out + (size_t)(b * 256 + w * 32) * 512 + h * 32;
#pragma unroll
  for (int j = 0; j < 4; ++j) {
    const int qrow = (g << 2) + j;
    const float i0 = 1.0f / __shfl(lsum0, qrow);
    const float i1 = 1.0f / __shfl(lsum1, qrow);
    ao[(qrow) * 512 + l16]            = f2bf(oacc[0][0][j] * i0);
    ao[(qrow) * 512 + 16 + l16]       = f2bf(oacc[0][1][j] * i0);
    ao[(16 + qrow) * 512 + l16]       = f2bf(oacc[1][0][j] * i1);
    ao[(16 + qrow) * 512 + 16 + l16]  = f2bf(oacc[1][1][j] * i1);
  }
}

// K2: out = attn @ proj_wT^T + proj_b  (gload_lds, 128x128 tile, swizzled LDS)
__global__ __launch_bounds__(256)
void proj_kernel(const unsigned short* __restrict__ A,    // [65536][512] bf16
                 const unsigned short* __restrict__ BT,   // [512][512] bf16
                 const float* __restrict__ proj_b,
                 float* __restrict__ out) {
  __shared__ short As[128 * 32];
  __shared__ short Bs[128 * 32];
  const int bid = blockIdx.x;
  const int m0 = (bid & 511) << 7, n0 = (bid >> 9) << 7;
  const int tid = threadIdx.x;
  const int w = tid >> 6, l = tid & 63, l16 = l & 15, g = l >> 4;
  const int wr = w >> 1, wc = w & 1;
  const int gsw8 = (g ^ ((l16 >> 1) & 3)) << 3;
  const int lrow = l >> 2;
  const int lcol = (((l & 3) ^ ((l >> 3) & 3)) << 3);

  const unsigned short* asrc0 = A + (size_t)(m0 + w * 16 + lrow) * 512 + lcol;
  const unsigned short* asrc1 = asrc0 + (size_t)64 * 512;
  const unsigned short* bsrc0 = BT + (size_t)(n0 + w * 16 + lrow) * 512 + lcol;
  const unsigned short* bsrc1 = bsrc0 + (size_t)64 * 512;
  short* ldsA0 = As + w * 512; short* ldsA1 = As + (4 + w) * 512;
  short* ldsB0 = Bs + w * 512; short* ldsB1 = Bs + (4 + w) * 512;

  f32x4v acc[4][4];
#pragma unroll
  for (int mt = 0; mt < 4; ++mt)
#pragma unroll
    for (int nt = 0; nt < 4; ++nt) acc[mt][nt] = (f32x4v)(0.0f);

  for (int k0 = 0; k0 < 512; k0 += 32) {
    GLOAD16(asrc0 + k0, ldsA0);
    GLOAD16(asrc1 + k0, ldsA1);
    GLOAD16(bsrc0 + k0, ldsB0);
    GLOAD16(bsrc1 + k0, ldsB1);
    __syncthreads();
    short8 af[4], bfr[4];
#pragma unroll
    for (int mt = 0; mt < 4; ++mt)
      af[mt] = *reinterpret_cast<short8*>(&As[(wr * 64 + mt * 16 + l16) * 32 + gsw8]);
#pragma unroll
    for (int nt = 0; nt < 4; ++nt)
      bfr[nt] = *reinterpret_cast<short8*>(&Bs[(wc * 64 + nt * 16 + l16) * 32 + gsw8]);
#pragma unroll
    for (int mt = 0; mt < 4; ++mt)
#pragma unroll
      for (int nt = 0; nt < 4; ++nt)
        acc[mt][nt] = __builtin_amdgcn_mfma_f32_16x16x32_bf16(af[mt], bfr[nt], acc[mt][nt], 0, 0, 0);
    __syncthreads();
  }
#pragma unroll
  for (int nt = 0; nt < 4; ++nt) {
    const int col = n0 + wc * 64 + nt * 16 + l16;
    const float pb = proj_b[col];
#pragma unroll
    for (int mt = 0; mt < 4; ++mt)
#pragma unroll
      for (int j = 0; j < 4; ++j)
        out[(size_t)(m0 + wr * 64 + mt * 16 + g * 4 + j) * 512 + col] = acc[mt][nt][j] + pb;
  }
}

extern "C" void kernel_launch(void* const* d_in, const int* in_sizes, int n_in,
                              void* d_out, int out_size, void* d_ws, size_t ws_size,
                              hipStream_t stream) {
  const float* x      = (const float*)d_in[0];
  const float* temb   = (const float*)d_in[1];
  const float* qkv_w  = (const float*)d_in[2];
  const float* qkv_b  = (const float*)d_in[3];
  const float* temb_w = (const float*)d_in[4];
  const float* temb_b = (const float*)d_in[5];
  const float* rpb    = (const float*)d_in[6];
  const float* proj_w = (const float*)d_in[7];
  const float* proj_b = (const float*)d_in[8];
  float* out = (float*)d_out;

  char* ws = (char*)d_ws;
  float* tm               = (float*)ws;                                  // 1,572,864 B
  unsigned short* xb16    = (unsigned short*)(ws + 1572864);             // 67,108,864 B
  unsigned short* qkv_wT  = (unsigned short*)(ws + 1572864 + 67108864);  // 1,572,864 B
  unsigned short* proj_wT = (unsigned short*)(ws + 1572864 + 67108864 + 1572864);  // 524,288 B
  unsigned short* attn_ws = (unsigned short*)(ws + 1572864 + 67108864 + 1572864 + 524288); // 67,108,864 B

  cvt_x_kernel<<<2048, 256, 0, stream>>>(x, xb16, (256 * 256 * 512) / 8);
  cvt_wT_kernel<<<16 * 24, 256, 0, stream>>>(qkv_w, qkv_wT, 1536);
  cvt_wT_kernel<<<16 * 8, 256, 0, stream>>>(proj_w, proj_wT, 512);
  temb_mod_kernel<<<64, 256, 0, stream>>>(temb, temb_w, temb_b, qkv_b, tm);
  fused_attn_kernel<<<B_ * H_, 512, 0, stream>>>(xb16, qkv_wT, rpb, tm, attn_ws);
  proj_kernel<<<512 * 4, 256, 0, stream>>>(attn_ws, proj_wT, proj_b, out);
}